// Round 14
// baseline (367.970 us; speedup 1.0000x reference)
//
#include <hip/hip_runtime.h>
#include <math.h>

// Fixed problem shapes (CausalSelfAttention: B=2, T=2048, C=1024, H=16)
#define B_ 2
#define T_ 2048
#define C_ 1024
#define H_ 16
#define D_ 64
#define M_ (B_*T_)   // 4096 rows

typedef __bf16 bf16x8 __attribute__((ext_vector_type(8)));
typedef __bf16 bf16x4 __attribute__((ext_vector_type(4)));
typedef float  f32x4  __attribute__((ext_vector_type(4)));
typedef float  f32x16 __attribute__((ext_vector_type(16)));

__device__ __forceinline__ unsigned short f2bf(float f) {
    unsigned int u = __float_as_uint(f);
    u += 0x7FFFu + ((u >> 16) & 1u);
    return (unsigned short)(u >> 16);
}

__device__ __forceinline__ bf16x8 pack4(unsigned a, unsigned b,
                                        unsigned c, unsigned d) {
    union { unsigned u[4]; bf16x8 v; } t;
    t.u[0] = a; t.u[1] = b; t.u[2] = c; t.u[3] = d;
    return t.v;
}

// async 16B global->LDS (wave-uniform LDS base + lane*16; global addr per-lane)
__device__ __forceinline__ void gload16(const void* g, void* l) {
    __builtin_amdgcn_global_load_lds(
        (const __attribute__((address_space(1))) void*)g,
        (__attribute__((address_space(3))) void*)l, 16, 0, 0);
}

// ---------------------------------------------------------------------------
// Fused prep: blocks [0,2048) convert query fp32->bf16 (8 elems/thread);
// blocks [2048,6144) transpose+convert the 4 weights (32x32 tiles).
// ---------------------------------------------------------------------------
__global__ __launch_bounds__(256) void prep_kernel(
    const float* __restrict__ X, unsigned short* __restrict__ Xb,
    const float* __restrict__ W0, const float* __restrict__ W1,
    const float* __restrict__ W2, const float* __restrict__ W3,
    unsigned short* __restrict__ T0, unsigned short* __restrict__ T1,
    unsigned short* __restrict__ T2, unsigned short* __restrict__ T3)
{
    const int tid = threadIdx.x;
    if (blockIdx.x < 2048) {
        const size_t i = ((size_t)blockIdx.x * 256 + tid) * 8;
        const float4 a = *(const float4*)&X[i];
        const float4 b = *(const float4*)&X[i + 4];
        ushort4 s0, s1;
        s0.x = f2bf(a.x); s0.y = f2bf(a.y); s0.z = f2bf(a.z); s0.w = f2bf(a.w);
        s1.x = f2bf(b.x); s1.y = f2bf(b.y); s1.z = f2bf(b.z); s1.w = f2bf(b.w);
        *(ushort4*)&Xb[i]     = s0;
        *(ushort4*)&Xb[i + 4] = s1;
        return;
    }
    const int bz = blockIdx.x - 2048;          // 0..4095
    const int z = bz >> 10, rem = bz & 1023;
    const float* W; unsigned short* Wt;
    switch (z) {
        case 0: W = W0; Wt = T0; break;
        case 1: W = W1; Wt = T1; break;
        case 2: W = W2; Wt = T2; break;
        default: W = W3; Wt = T3; break;
    }
    __shared__ unsigned short tile[32][33];
    const int k0 = (rem >> 5) * 32, n0 = (rem & 31) * 32;
    {
        const int r = tid >> 3, c = (tid & 7) * 4;
        const float4 v = *(const float4*)&W[(size_t)(k0 + r)*C_ + n0 + c];
        tile[c+0][r] = f2bf(v.x);
        tile[c+1][r] = f2bf(v.y);
        tile[c+2][r] = f2bf(v.z);
        tile[c+3][r] = f2bf(v.w);
    }
    __syncthreads();
    {
        const int r = tid >> 3, c = (tid & 7) * 4;
        ushort4 s;
        s.x = tile[r][c+0]; s.y = tile[r][c+1]; s.z = tile[r][c+2]; s.w = tile[r][c+3];
        *(ushort4*)&Wt[(size_t)(n0 + r)*C_ + k0 + c] = s;
    }
}

// ---------------------------------------------------------------------------
// Output projection GEMM v3: 64x128 tile, BK=32, 4-slot LDS ring (48 KB),
// counted vmcnt, in-phase staging. Verified r12 (neutral-to-equal vs m97).
// Grid (8,64) = 512 blocks = 2 blocks/CU.
// ---------------------------------------------------------------------------
__global__ __launch_bounds__(256) void gemm_proj_kernel(
    const unsigned short* __restrict__ A, const unsigned short* __restrict__ Bt,
    const float* __restrict__ bias, float* __restrict__ out)
{
    __shared__ __align__(16) unsigned short lds[4 * 6144];   // 48 KB ring

    const int tid  = threadIdx.x;
    const int lane = tid & 63;
    const int wave = tid >> 6;                 // 0..3
    const int wm = wave >> 1, wn = wave & 1;
    const int l15 = lane & 15, quad = lane >> 4;
    const int m0 = blockIdx.y * 64, n0 = blockIdx.x * 128;

    const int lrow = lane >> 2;
    const int csw  = ((lane & 3) ^ ((lane >> 3) & 3)) * 8;   // swizzled src col
    const int sw8  = (quad ^ ((l15 >> 1) & 3)) * 8;          // swizzled read slot

#define PSTAGE(tt) do {                                                        \
        const int bi_ = ((tt) & 3) * 6144;                                     \
        const int k0_ = (tt) << 5;                                             \
        gload16(&A [(size_t)(m0 + wave*16 + lrow)*C_ + k0_ + csw],             \
                &lds[bi_ + wave*512]);                                         \
        gload16(&Bt[(size_t)(n0 + wave*32 + lrow)*C_ + k0_ + csw],             \
                &lds[bi_ + 2048 + wave*1024]);                                 \
        gload16(&Bt[(size_t)(n0 + wave*32 + 16 + lrow)*C_ + k0_ + csw],        \
                &lds[bi_ + 2048 + wave*1024 + 512]);                           \
    } while (0)

    const f32x4 zero4 = {0.f, 0.f, 0.f, 0.f};
    f32x4 acc[2][4];
    #pragma unroll
    for (int i = 0; i < 2; ++i)
        #pragma unroll
        for (int j = 0; j < 4; ++j) acc[i][j] = zero4;

    PSTAGE(0); PSTAGE(1); PSTAGE(2);    // 9 loads in flight (3 tiles deep)

    for (int t = 0; t < 32; ++t) {
        const int bi = (t & 3) * 6144;
        __builtin_amdgcn_s_barrier();            // all done reading slot (t-1)&3
        __builtin_amdgcn_sched_barrier(0);
        // tile-t residency: t's 3 loads are the oldest outstanding
        if (t <= 29) {
            asm volatile("s_waitcnt vmcnt(6)" ::: "memory");
        } else if (t == 30) {
            asm volatile("s_waitcnt vmcnt(3)" ::: "memory");
        } else {
            asm volatile("s_waitcnt vmcnt(0)" ::: "memory");
        }
        __builtin_amdgcn_s_barrier();            // tile t resident for ALL waves
        __builtin_amdgcn_sched_barrier(0);

        const unsigned short* Ab = &lds[bi];
        const unsigned short* Bb = &lds[bi + 2048];

        bf16x8 af[2], bfr[4];
        #pragma unroll
        for (int i = 0; i < 2; ++i)
            af[i] = *(const bf16x8*)&Ab[(wm*32 + i*16 + l15)*32 + sw8];
        #pragma unroll
        for (int j = 0; j < 4; ++j)
            bfr[j] = *(const bf16x8*)&Bb[(wn*64 + j*16 + l15)*32 + sw8];

        if (t < 29) PSTAGE(t + 3);               // staged under the MFMA shadow

        __builtin_amdgcn_s_setprio(1);
        #pragma unroll
        for (int i = 0; i < 2; ++i)
            #pragma unroll
            for (int j = 0; j < 4; ++j)
                acc[i][j] = __builtin_amdgcn_mfma_f32_16x16x32_bf16(
                    af[i], bfr[j], acc[i][j], 0, 0, 0);
        __builtin_amdgcn_s_setprio(0);
    }
#undef PSTAGE

    #pragma unroll
    for (int j = 0; j < 4; ++j) {
        const int n = n0 + wn*64 + j*16 + l15;
        const float bv = bias[n];
        #pragma unroll
        for (int i = 0; i < 2; ++i)
            #pragma unroll
            for (int r = 0; r < 4; ++r) {
                const int m = m0 + wm*32 + i*16 + quad*4 + r;
                out[(size_t)m*C_ + n] = acc[i][j][r] + bv;
            }
    }
}

// ---------------------------------------------------------------------------
// QKV GEMM v5: 256x256 tile, 8 waves, BK=32 — v4's in-phase staging with a
// 2-SLOT ring (64 KB) -> 2 blocks/CU (was 1 at 128 KB). Rationale: in-phase
// staging gives each load ~1 compute-phase (~500 cyc) of cover, so depth-1
// prefetch suffices; the freed LDS doubles resident blocks, adding the m114
// inter-block overlap that every other kernel here already exploits
// (r3 proj 1->2 blocks/CU ~2x). Tile-top wait is vmcnt(0): only the tile's
// own 4 loads are outstanding there, issued one compute-phase earlier.
// Staging targets the slot freed by the top barrier (same race argument as
// v4, depth 1). Epilogue staging halved to 8 KB/wave (2 within-wave passes,
// no new barriers) to fit the 64 KB ring. T1 XCD swizzle unchanged.
// ---------------------------------------------------------------------------
__global__ __launch_bounds__(512, 4) void gemm256_qkv_kernel(
    const unsigned short* __restrict__ A, const unsigned short* __restrict__ Bt,
    const float* __restrict__ b0, const float* __restrict__ b1,
    const float* __restrict__ b2,
    unsigned short* __restrict__ outq, unsigned short* __restrict__ outk,
    unsigned short* __restrict__ outv)
{
    __shared__ __align__(16) unsigned short lds[2 * 16384];   // 64 KB ring

    const int tid  = threadIdx.x;
    const int lane = tid & 63;
    const int wave = tid >> 6;
    const int l15  = lane & 15, quad = lane >> 4;
    const int wm   = wave >> 2, wn = wave & 3;
    // T1: XCD-aware bijective block swizzle (grid (12,16) = 192 = 8*24)
    const int bid  = blockIdx.y * 12 + blockIdx.x;
    const int swz  = (bid & 7) * 24 + (bid >> 3);
    const int m0   = (swz / 12) * 256, n0 = (swz % 12) * 256;

    const int lrow = lane >> 2;
    const int csw  = ((lane & 3) ^ ((lane >> 3) & 3)) * 8;   // swizzled src col (ushorts)
    const int sw8  = (quad ^ ((l15 >> 1) & 3)) * 8;          // swizzled read slot (ushorts)

    // half h of a tile's staging: h=0 -> rows +0/16 base; h=1 -> rows +16.
#define STAGE_H(tt, h) do {                                                    \
        const int bi_ = ((tt) & 1) << 14;                                      \
        const int k0_ = (tt) << 5;                                             \
        const int ra_ = m0 + wave*32 + (h)*16 + lrow;                          \
        const int rb_ = n0 + wave*32 + (h)*16 + lrow;                          \
        gload16(&A [(size_t)ra_*C_ + k0_ + csw],                               \
                &lds[bi_ + wave*1024 + (h)*512]);                              \
        gload16(&Bt[(size_t)rb_*C_ + k0_ + csw],                               \
                &lds[bi_ + 8192 + wave*1024 + (h)*512]);                       \
    } while (0)

    const f32x4 zero4 = {0.f, 0.f, 0.f, 0.f};
    f32x4 acc[8][4];
    #pragma unroll
    for (int i = 0; i < 8; ++i)
        #pragma unroll
        for (int j = 0; j < 4; ++j) acc[i][j] = zero4;

    STAGE_H(0,0); STAGE_H(0,1);       // tile 0 in flight (4 loads)

    for (int t = 0; t < 32; ++t) {
        const int bi = (t & 1) << 14;
        __builtin_amdgcn_s_barrier();            // everyone done reading slot t^1
        __builtin_amdgcn_sched_barrier(0);
        // only tile t's own 4 loads are outstanding here (issued 1 phase ago)
        asm volatile("s_waitcnt vmcnt(0)" ::: "memory");
        __builtin_amdgcn_s_barrier();            // tile t resident for ALL waves
        __builtin_amdgcn_sched_barrier(0);

        const unsigned short* Ab = &lds[bi];
        const unsigned short* Bb = &lds[bi + 8192];

        // ---- phase 1: rows [0,64); stage half 0 of tile t+1 under MFMA ----
        bf16x8 bfr[4], af[4];
        #pragma unroll
        for (int j = 0; j < 4; ++j)
            bfr[j] = *(const bf16x8*)&Bb[(wn*64 + j*16 + l15)*32 + sw8];
        #pragma unroll
        for (int i = 0; i < 4; ++i)
            af[i] = *(const bf16x8*)&Ab[(wm*128 + i*16 + l15)*32 + sw8];

        if (t < 31) STAGE_H(t + 1, 0);

        __builtin_amdgcn_s_setprio(1);
        #pragma unroll
        for (int i = 0; i < 4; ++i)
            #pragma unroll
            for (int j = 0; j < 4; ++j)
                acc[i][j] = __builtin_amdgcn_mfma_f32_16x16x32_bf16(
                    af[i], bfr[j], acc[i][j], 0, 0, 0);
        __builtin_amdgcn_s_setprio(0);

        // ---- phase split: issue-order diversity across waves ----
        __builtin_amdgcn_s_barrier();
        __builtin_amdgcn_sched_barrier(0);

        // ---- phase 2: rows [64,128); stage half 1 of tile t+1 ----
        #pragma unroll
        for (int i = 0; i < 4; ++i)
            af[i] = *(const bf16x8*)&Ab[(wm*128 + 64 + i*16 + l15)*32 + sw8];

        if (t < 31) STAGE_H(t + 1, 1);

        __builtin_amdgcn_s_setprio(1);
        #pragma unroll
        for (int i = 0; i < 4; ++i)
            #pragma unroll
            for (int j = 0; j < 4; ++j)
                acc[4+i][j] = __builtin_amdgcn_mfma_f32_16x16x32_bf16(
                    af[i], bfr[j], acc[4+i][j], 0, 0, 0);
        __builtin_amdgcn_s_setprio(0);
    }
#undef STAGE_H

    // ---- epilogue: ring reused as 8 x 8 KB wave-private staging (2 passes,
    //      purely within-wave: write own region, read own region) ----
    __syncthreads();   // full drain + barrier (one-time)

    unsigned short* Ep = &lds[wave * 4096];      // 8 KB per wave
    const int which = n0 >> 10;                  // 0=q 1=k 2=v
    const int c0 = (n0 & 1023) + wn * 64;        // col within matrix (head base)
    const int h  = c0 >> 6;
    const int bb = m0 >> 11;
    const int t0 = (m0 & (T_ - 1)) + wm * 128;
    const int bh = bb * H_ + h;
    const float* bp = (which == 0) ? b0 : (which == 1 ? b1 : b2);
    // q pre-scale folds softmax 1/sqrt(d) AND 1/ln2 (exp2-direct in flash):
    const float qscale = (which == 0) ? 0.18033688f : 1.0f;   // 0.125/ln(2)

    if (which < 2) {
        // two 64-row halves: [local t=64][d=64] row-major, then coalesced store
        unsigned short* op = (which == 0) ? outq : outk;
        __bf16* Eb = (__bf16*)Ep;
        const int row8 = lane >> 3, chunk = lane & 7;
        #pragma unroll
        for (int hb = 0; hb < 2; ++hb) {
            #pragma unroll
            for (int j = 0; j < 4; ++j) {
                const int cl = j*16 + l15;
                const float bias = bp[c0 + cl];
                #pragma unroll
                for (int i = 0; i < 4; ++i)
                    #pragma unroll
                    for (int r = 0; r < 4; ++r)
                        Eb[(i*16 + quad*4 + r)*64 + cl] =
                            (__bf16)((acc[hb*4 + i][j][r] + bias) * qscale);
            }
            #pragma unroll
            for (int u = 0; u < 8; ++u) {
                const int row = u*8 + row8;      // local row 0..63
                const uint4 v = *(const uint4*)&Ep[row*64 + chunk*8];
                *(uint4*)&op[((size_t)bh*T_ + t0 + hb*64 + row)*D_ + chunk*8] = v;
            }
        }
    } else {
        // two 32-d halves: [local d=32][t=128] with XOR slot swizzle
        const int d4 = lane >> 4, chunk = lane & 15;
        #pragma unroll
        for (int hb = 0; hb < 2; ++hb) {
            #pragma unroll
            for (int j = 0; j < 2; ++j) {
                const int cl = (hb*2 + j)*16 + l15;   // d within head, 0..63
                const float bias = bp[c0 + cl];
                const int lcl = cl - hb*32;           // local d 0..31
                const int xo = (cl & 7) * 8;
                #pragma unroll
                for (int i = 0; i < 8; ++i) {
                    bf16x4 pk = {(__bf16)(acc[i][hb*2 + j][0] + bias),
                                 (__bf16)(acc[i][hb*2 + j][1] + bias),
                                 (__bf16)(acc[i][hb*2 + j][2] + bias),
                                 (__bf16)(acc[i][hb*2 + j][3] + bias)};
                    *(bf16x4*)&Ep[lcl*128 + ((i*16 + quad*4) ^ xo)] = pk;
                }
            }
            #pragma unroll
            for (int u = 0; u < 8; ++u) {
                const int d = hb*32 + u*4 + d4;
                const uint4 v = *(const uint4*)
                    &Ep[(d - hb*32)*128 + ((chunk*8) ^ ((d & 7)*8))];
                *(uint4*)&outv[((size_t)bh*D_ + d)*T_ + t0 + chunk*8] = v;
            }
        }
    }
}

// ---------------------------------------------------------------------------
// MFMA flash attention v8: 32x32x16 MFMA + in-register softmax (T12).
// Verified rounds 7-12 (~42 us). Four alternative schedules all measured
// slower — this two-barrier schedule is the verified optimum.
// ---------------------------------------------------------------------------
__global__ __launch_bounds__(256) void flash_mfma_kernel(
    const unsigned short* __restrict__ Qs, const unsigned short* __restrict__ Ks,
    const unsigned short* __restrict__ Vts, unsigned short* __restrict__ Y,
    float* __restrict__ parts, float* __restrict__ lbase)
{
    __shared__ __align__(16) unsigned short Kls[64 * 64];   // 8 KB, swizzled
    __shared__ __align__(16) unsigned short Vls[64 * 64];   // 8 KB, swizzled
    __shared__ float lsums[4][32];

    const int tid  = threadIdx.x;
    const int lane = tid & 63, wave = tid >> 6;
    const int krl  = lane & 31, hi = lane >> 5;
    const int srow8 = lane >> 3;                  // 0..7 (staging row-in-cu)
    const int schk8 = ((lane & 7) ^ srow8) * 8;   // pre-swizzled src chunk (ushorts)
    const int job  = blockIdx.x >> 5;    // 0..15
    const int bh   = blockIdx.x & 31;
    const bool isA = (job < 8);
    const int a    = isA ? job : job - 8;

    int qts[2], slos[2], shis[2], slots[2], nseg;
    if (isA) {
        qts[0] = a;      slos[0] = 0;        shis[0] = 2*a + 2;  slots[0] = -1;
        qts[1] = 15 - a; slos[1] = 0;        shis[1] = 15 - 2*a; slots[1] = 0;
        nseg = 2;
    } else {
        qts[0] = 15 - a; slos[0] = 15 - 2*a; shis[0] = 32 - 2*a; slots[0] = 1;
        nseg = 1;
    }

    const int b_ = bh >> 4, h_ = bh & (H_ - 1);

#define FSTAGE(itv) do {                                                       \
        const int s0_ = (itv) * 64;                                            \
        const int cu0_ = 2*wave, cu1_ = 2*wave + 1;                            \
        const int r0_ = cu0_*8 + srow8, r1_ = cu1_*8 + srow8;                  \
        gload16(&Ks [((size_t)bh*T_ + s0_ + r0_)*D_ + schk8],                  \
                (char*)Kls + cu0_*1024);                                       \
        gload16(&Vts[((size_t)bh*D_ + r0_)*T_ + s0_ + schk8],                  \
                (char*)Vls + cu0_*1024);                                       \
        gload16(&Ks [((size_t)bh*T_ + s0_ + r1_)*D_ + schk8],                  \
                (char*)Kls + cu1_*1024);                                       \
        gload16(&Vts[((size_t)bh*D_ + r1_)*T_ + s0_ + schk8],                  \
                (char*)Vls + cu1_*1024);                                       \
    } while (0)

    for (int sg = 0; sg < nseg; ++sg) {
        const int qt  = qts[sg];
        const int qw0 = qt * 128 + wave * 32;
        const int qrow = qw0 + krl;              // this lane's q-column

        // Q fragments (B-operand, d-slices of 16): contiguous 16B from global
        bf16x8 qf[4];
        #pragma unroll
        for (int ds = 0; ds < 4; ++ds)
            qf[ds] = *(const bf16x8*)&Qs[((size_t)bh*T_ + qrow)*D_ + ds*16 + hi*8];

        f32x16 o[2];
        #pragma unroll
        for (int dt = 0; dt < 2; ++dt)
            #pragma unroll
            for (int r = 0; r < 16; ++r) o[dt][r] = 0.f;
        float lsum = 0.f;

        for (int it = slos[sg]; it < shis[sg]; ++it) {
            const int s0 = it * 64;
            __syncthreads();
            FSTAGE(it);
            __syncthreads();

            if (s0 > qw0 + 31) continue;   // wave fully masked (uniform barriers)

            // ---- S^T = K·Q^T (2 k-tiles x 4 d-slices, 32x32x16) ----
            f32x16 st[2];
            #pragma unroll
            for (int kt = 0; kt < 2; ++kt)
                #pragma unroll
                for (int r = 0; r < 16; ++r) st[kt][r] = 0.f;
            #pragma unroll
            for (int kt = 0; kt < 2; ++kt) {
                #pragma unroll
                for (int ds = 0; ds < 4; ++ds) {
                    const int row = kt*32 + krl;
                    bf16x8 kf = *(const bf16x8*)
                        &Kls[row*64 + (((ds*2 + hi) ^ (krl & 7)) << 3)];
                    st[kt] = __builtin_amdgcn_mfma_f32_32x32x16_bf16(
                        kf, qf[ds], st[kt], 0, 0, 0);
                }
            }

            // ---- p = 2^s (+ causal mask), in-register; accumulate lsum ----
            const bool diag = (s0 + 63 > qw0);
            #pragma unroll
            for (int kt = 0; kt < 2; ++kt) {
                const int kb = s0 + kt*32 + 4*hi;
                #pragma unroll
                for (int reg = 0; reg < 16; ++reg) {
                    const int crow = (reg & 3) + 8*(reg >> 2);
                    float e = __builtin_amdgcn_exp2f(st[kt][reg]);
                    if (diag && (kb + crow > qrow)) e = 0.f;
                    st[kt][reg] = e;
                    lsum += e;
                }
            }

            // ---- pack P -> PV A-fragments (cvt_pk + permlane32_swap) ----
            bf16x8 pa[4];
            #pragma unroll
            for (int kt = 0; kt < 2; ++kt) {
                #pragma unroll
                for (int hh = 0; hh < 2; ++hh) {
                    const int rb = hh * 8;
                    unsigned c0, c1, c2, c3;
                    asm("v_cvt_pk_bf16_f32 %0, %1, %2"
                        : "=v"(c0) : "v"(st[kt][rb+0]), "v"(st[kt][rb+1]));
                    asm("v_cvt_pk_bf16_f32 %0, %1, %2"
                        : "=v"(c1) : "v"(st[kt][rb+2]), "v"(st[kt][rb+3]));
                    asm("v_cvt_pk_bf16_f32 %0, %1, %2"
                        : "=v"(c2) : "v"(st[kt][rb+4]), "v"(st[kt][rb+5]));
                    asm("v_cvt_pk_bf16_f32 %0, %1, %2"
                        : "=v"(c3) : "v"(st[kt][rb+6]), "v"(st[kt][rb+7]));
                    asm("v_permlane32_swap_b32 %0, %1" : "+v"(c0), "+v"(c2));
                    asm("v_permlane32_swap_b32 %0, %1" : "+v"(c1), "+v"(c3));
                    pa[kt*2 + hh] = pack4(c0, c1, c2, c3);
                }
            }

            // ---- O += P·V (2 d-tiles x 4 k-slices, 32x32x16) ----
            #pragma unroll
            for (int dt = 0; dt < 2; ++dt) {
                #pragma unroll
                for (int ks = 0; ks < 4; ++ks) {
                    const int rowd = dt*32 + krl;
                    bf16x8 vb = *(const bf16x8*)
                        &Vls[rowd*64 + (((ks*2 + hi) ^ (krl & 7)) << 3)];
                    o[dt] = __builtin_amdgcn_mfma_f32_32x32x16_bf16(
                        pa[ks], vb, o[dt], 0, 0, 0);
                }
            }
        }

        // ---- combine lane-halves of lsum; publish per-q sums ----
        lsum += __shfl_xor(lsum, 32, 64);
        if (lane < 32) lsums[wave][krl] = lsum;

        if (slots[sg] < 0) {
            // direct write Y bf16 (O layout: col d = krl, row q = crow+4*hi)
            #pragma unroll
            for (int reg = 0; reg < 16; ++reg) {
                const int q = (reg & 3) + 8*(reg >> 2) + 4*hi;
                const float inv = 1.0f / lsums[wave][q];
                const size_t yb = ((size_t)(b_*T_ + qw0 + q))*C_ + h_*D_;
                *(__bf16*)&Y[yb + krl]      = (__bf16)(o[0][reg] * inv);
                *(__bf16*)&Y[yb + 32 + krl] = (__bf16)(o[1][reg] * inv);
            }
        } else {
            // partial: fp32 O [128][64] + l [128] into slot
            const int gpi = bh*16 + a*2 + slots[sg];
            float* Op = parts + (size_t)gpi*8192;
            float* Lp = lbase + gpi*128;
            if (lane < 32) Lp[wave*32 + lane] = lsum;
            #pragma unroll
            for (int reg = 0; reg < 16; ++reg) {
                const int tl = wave*32 + (reg & 3) + 8*(reg >> 2) + 4*hi;
                Op[(size_t)tl*64 + krl]      = o[0][reg];
                Op[(size_t)tl*64 + 32 + krl] = o[1][reg];
            }
        }
    }
#undef FSTAGE
}

// ---------------------------------------------------------------------------
// Merge split partials: Y = (O0+O1)/(l0+l1), bf16. Grid 256 (32 bh x 8 pairs).
// Pair p merges qt = 15-p from slots (bh*16+p*2, +1); O is [128][64].
// ---------------------------------------------------------------------------
__global__ __launch_bounds__(256) void merge_kernel(
    const float* __restrict__ parts, const float* __restrict__ lbase,
    unsigned short* __restrict__ Y)
{
    const int pair = blockIdx.x;          // 0..255
    const int bh = pair >> 3, p = pair & 7;
    const int qt = 15 - p;
    const int g0 = bh*16 + p*2;
    const float* O0 = parts + (size_t)g0*8192;
    const float* O1 = O0 + 8192;
    const float* L0 = lbase + g0*128;
    const float* L1 = L0 + 128;

    const int tid = threadIdx.x;
    const int r = tid >> 1, c0 = (tid & 1) * 32;
    const float inv = 1.0f / (L0[r] + L1[r]);
    const int b = bh >> 4, h = bh & (H_ - 1);
    const int t = qt*128 + r;
    #pragma unroll
    for (int k = 0; k < 8; ++k) {
        const f32x4 a  = *(const f32x4*)&O0[(size_t)r*64 + c0 + k*4];
        const f32x4 bb = *(const f32x4*)&O1[(size_t)r*64 + c0 + k*4];
        bf16x4 pk = {(__bf16)((a[0]+bb[0])*inv), (__bf16)((a[1]+bb[1])*inv),
                     (__bf16)((a[2]+bb[2])*inv), (__bf16)((a[3]+bb[3])*inv)};
        *(bf16x4*)&Y[((size_t)(b*T_ + t))*C_ + h*D_ + c0 + k*4] = pk;
    }
}

// ---------------------------------------------------------------------------
extern "C" void kernel_launch(void* const* d_in, const int* in_sizes, int n_in,
                              void* d_out, int out_size, void* d_ws, size_t ws_size,
                              hipStream_t stream) {
    const float* query = (const float*)d_in[0];
    const float* Wq = (const float*)d_in[1];
    const float* bq = (const float*)d_in[2];
    const float* Wk = (const float*)d_in[3];
    const float* bk = (const float*)d_in[4];
    const float* Wv = (const float*)d_in[5];
    const float* bv = (const float*)d_in[6];
    const float* Wp = (const float*)d_in[7];
    const float* bp = (const float*)d_in[8];
    float* out = (float*)d_out;

    // Workspace layout (bytes), total 50.33 MB:
    //   [0,       8.39M)  q bf16 [bh][t][d], pre-scaled by 0.125/ln2
    //   [8.39M,  16.78M)  k bf16 [bh][t][d]
    //   [16.78M, 25.17M)  v bf16 [bh][d][t] (transposed)
    //   [25.17M, 27.26M)  WtP   bf16 (Wp^T)
    //   [27.26M, 33.55M)  WtQKV bf16; dead after QKV GEMM -> lbase (512x128 f32)
    //   [33.55M, 41.94M)  yb    bf16 [B*T][C] (attention output)
    //   [41.94M, 50.33M)  qx    bf16 query (dead after QKV GEMM)
    // Flash O-partials (512 x 32KB fp32 = 16.78MB) live in d_out, which is
    // dead until the proj GEMM overwrites it at the end.
    char* ws = (char*)d_ws;
    unsigned short* qbf   = (unsigned short*)(ws);
    unsigned short* kbf   = (unsigned short*)(ws + 8388608);
    unsigned short* vtbf  = (unsigned short*)(ws + 16777216);
    unsigned short* WtP   = (unsigned short*)(ws + 25165824);
    unsigned short* WtQKV = (unsigned short*)(ws + 27262976);
    unsigned short* yb    = (unsigned short*)(ws + 33554432);
    unsigned short* qx    = (unsigned short*)(ws + 41943040);
    float* lbase = (float*)(ws + 27262976);             // 512 x 128 floats
    float* parts = out;                                 // 512 x 8192 floats

    prep_kernel<<<6144, 256, 0, stream>>>(
        query, qx, Wq, Wk, Wv, Wp,
        WtQKV, WtQKV + (size_t)C_*C_, WtQKV + 2*(size_t)C_*C_, WtP);

    // Fused QKV GEMM v5: M=4096, N=3072, 2-slot ring, 2 blocks/CU
    gemm256_qkv_kernel<<<dim3(12, 16), 512, 0, stream>>>(
        qx, WtQKV, bq, bk, bv, qbf, kbf, vtbf);

    flash_mfma_kernel<<<512, 256, 0, stream>>>(qbf, kbf, vtbf, yb, parts, lbase);
    merge_kernel<<<256, 256, 0, stream>>>(parts, lbase, yb);

    // Output projection v3: M=4096, N=1024, in-phase-staged ring
    gemm_proj_kernel<<<dim3(C_/128, M_/64), 256, 0, stream>>>(
        yb, WtP, bp, out);
}

// Round 15
// 184.990 us; speedup vs baseline: 1.9891x; 1.9891x over previous
//
#include <hip/hip_runtime.h>
#include <math.h>

// Fixed problem shapes (CausalSelfAttention: B=2, T=2048, C=1024, H=16)
#define B_ 2
#define T_ 2048
#define C_ 1024
#define H_ 16
#define D_ 64
#define M_ (B_*T_)   // 4096 rows

typedef __bf16 bf16x8 __attribute__((ext_vector_type(8)));
typedef __bf16 bf16x4 __attribute__((ext_vector_type(4)));
typedef float  f32x4  __attribute__((ext_vector_type(4)));
typedef float  f32x16 __attribute__((ext_vector_type(16)));

__device__ __forceinline__ unsigned short f2bf(float f) {
    unsigned int u = __float_as_uint(f);
    u += 0x7FFFu + ((u >> 16) & 1u);
    return (unsigned short)(u >> 16);
}

__device__ __forceinline__ bf16x8 pack4(unsigned a, unsigned b,
                                        unsigned c, unsigned d) {
    union { unsigned u[4]; bf16x8 v; } t;
    t.u[0] = a; t.u[1] = b; t.u[2] = c; t.u[3] = d;
    return t.v;
}

// async 16B global->LDS (wave-uniform LDS base + lane*16; global addr per-lane)
__device__ __forceinline__ void gload16(const void* g, void* l) {
    __builtin_amdgcn_global_load_lds(
        (const __attribute__((address_space(1))) void*)g,
        (__attribute__((address_space(3))) void*)l, 16, 0, 0);
}

// ---------------------------------------------------------------------------
// Fused prep: blocks [0,2048) convert query fp32->bf16 (8 elems/thread);
// blocks [2048,6144) transpose+convert the 4 weights (32x32 tiles).
// ---------------------------------------------------------------------------
__global__ __launch_bounds__(256) void prep_kernel(
    const float* __restrict__ X, unsigned short* __restrict__ Xb,
    const float* __restrict__ W0, const float* __restrict__ W1,
    const float* __restrict__ W2, const float* __restrict__ W3,
    unsigned short* __restrict__ T0, unsigned short* __restrict__ T1,
    unsigned short* __restrict__ T2, unsigned short* __restrict__ T3)
{
    const int tid = threadIdx.x;
    if (blockIdx.x < 2048) {
        const size_t i = ((size_t)blockIdx.x * 256 + tid) * 8;
        const float4 a = *(const float4*)&X[i];
        const float4 b = *(const float4*)&X[i + 4];
        ushort4 s0, s1;
        s0.x = f2bf(a.x); s0.y = f2bf(a.y); s0.z = f2bf(a.z); s0.w = f2bf(a.w);
        s1.x = f2bf(b.x); s1.y = f2bf(b.y); s1.z = f2bf(b.z); s1.w = f2bf(b.w);
        *(ushort4*)&Xb[i]     = s0;
        *(ushort4*)&Xb[i + 4] = s1;
        return;
    }
    const int bz = blockIdx.x - 2048;          // 0..4095
    const int z = bz >> 10, rem = bz & 1023;
    const float* W; unsigned short* Wt;
    switch (z) {
        case 0: W = W0; Wt = T0; break;
        case 1: W = W1; Wt = T1; break;
        case 2: W = W2; Wt = T2; break;
        default: W = W3; Wt = T3; break;
    }
    __shared__ unsigned short tile[32][33];
    const int k0 = (rem >> 5) * 32, n0 = (rem & 31) * 32;
    {
        const int r = tid >> 3, c = (tid & 7) * 4;
        const float4 v = *(const float4*)&W[(size_t)(k0 + r)*C_ + n0 + c];
        tile[c+0][r] = f2bf(v.x);
        tile[c+1][r] = f2bf(v.y);
        tile[c+2][r] = f2bf(v.z);
        tile[c+3][r] = f2bf(v.w);
    }
    __syncthreads();
    {
        const int r = tid >> 3, c = (tid & 7) * 4;
        ushort4 s;
        s.x = tile[r][c+0]; s.y = tile[r][c+1]; s.z = tile[r][c+2]; s.w = tile[r][c+3];
        *(ushort4*)&Wt[(size_t)(n0 + r)*C_ + k0 + c] = s;
    }
}

// ---------------------------------------------------------------------------
// Output projection GEMM v3: 64x128 tile, BK=32, 4-slot LDS ring (48 KB),
// counted vmcnt, in-phase staging. Verified r12.
// Grid (8,64) = 512 blocks = 2 blocks/CU.
// ---------------------------------------------------------------------------
__global__ __launch_bounds__(256) void gemm_proj_kernel(
    const unsigned short* __restrict__ A, const unsigned short* __restrict__ Bt,
    const float* __restrict__ bias, float* __restrict__ out)
{
    __shared__ __align__(16) unsigned short lds[4 * 6144];   // 48 KB ring

    const int tid  = threadIdx.x;
    const int lane = tid & 63;
    const int wave = tid >> 6;                 // 0..3
    const int wm = wave >> 1, wn = wave & 1;
    const int l15 = lane & 15, quad = lane >> 4;
    const int m0 = blockIdx.y * 64, n0 = blockIdx.x * 128;

    const int lrow = lane >> 2;
    const int csw  = ((lane & 3) ^ ((lane >> 3) & 3)) * 8;   // swizzled src col
    const int sw8  = (quad ^ ((l15 >> 1) & 3)) * 8;          // swizzled read slot

#define PSTAGE(tt) do {                                                        \
        const int bi_ = ((tt) & 3) * 6144;                                     \
        const int k0_ = (tt) << 5;                                             \
        gload16(&A [(size_t)(m0 + wave*16 + lrow)*C_ + k0_ + csw],             \
                &lds[bi_ + wave*512]);                                         \
        gload16(&Bt[(size_t)(n0 + wave*32 + lrow)*C_ + k0_ + csw],             \
                &lds[bi_ + 2048 + wave*1024]);                                 \
        gload16(&Bt[(size_t)(n0 + wave*32 + 16 + lrow)*C_ + k0_ + csw],        \
                &lds[bi_ + 2048 + wave*1024 + 512]);                           \
    } while (0)

    const f32x4 zero4 = {0.f, 0.f, 0.f, 0.f};
    f32x4 acc[2][4];
    #pragma unroll
    for (int i = 0; i < 2; ++i)
        #pragma unroll
        for (int j = 0; j < 4; ++j) acc[i][j] = zero4;

    PSTAGE(0); PSTAGE(1); PSTAGE(2);    // 9 loads in flight (3 tiles deep)

    for (int t = 0; t < 32; ++t) {
        const int bi = (t & 3) * 6144;
        __builtin_amdgcn_s_barrier();            // all done reading slot (t-1)&3
        __builtin_amdgcn_sched_barrier(0);
        // tile-t residency: t's 3 loads are the oldest outstanding
        if (t <= 29) {
            asm volatile("s_waitcnt vmcnt(6)" ::: "memory");
        } else if (t == 30) {
            asm volatile("s_waitcnt vmcnt(3)" ::: "memory");
        } else {
            asm volatile("s_waitcnt vmcnt(0)" ::: "memory");
        }
        __builtin_amdgcn_s_barrier();            // tile t resident for ALL waves
        __builtin_amdgcn_sched_barrier(0);

        const unsigned short* Ab = &lds[bi];
        const unsigned short* Bb = &lds[bi + 2048];

        bf16x8 af[2], bfr[4];
        #pragma unroll
        for (int i = 0; i < 2; ++i)
            af[i] = *(const bf16x8*)&Ab[(wm*32 + i*16 + l15)*32 + sw8];
        #pragma unroll
        for (int j = 0; j < 4; ++j)
            bfr[j] = *(const bf16x8*)&Bb[(wn*64 + j*16 + l15)*32 + sw8];

        if (t < 29) PSTAGE(t + 3);               // staged under the MFMA shadow

        __builtin_amdgcn_s_setprio(1);
        #pragma unroll
        for (int i = 0; i < 2; ++i)
            #pragma unroll
            for (int j = 0; j < 4; ++j)
                acc[i][j] = __builtin_amdgcn_mfma_f32_16x16x32_bf16(
                    af[i], bfr[j], acc[i][j], 0, 0, 0);
        __builtin_amdgcn_s_setprio(0);
    }
#undef PSTAGE

    #pragma unroll
    for (int j = 0; j < 4; ++j) {
        const int n = n0 + wn*64 + j*16 + l15;
        const float bv = bias[n];
        #pragma unroll
        for (int i = 0; i < 2; ++i)
            #pragma unroll
            for (int r = 0; r < 4; ++r) {
                const int m = m0 + wm*32 + i*16 + quad*4 + r;
                out[(size_t)m*C_ + n] = acc[i][j][r] + bv;
            }
    }
}

// ---------------------------------------------------------------------------
// QKV GEMM v5b: 256x256 tile, 8 waves, BK=32, 2-SLOT ring (64 KB) with
// in-phase depth-1 staging. ROUND-13 FIX: __launch_bounds__(512, 2) — the
// (512,4) annotation capped VGPRs at 64 and spilled acc[8][4] to scratch
// (VGPR_Count=64, WRITE_SIZE=512MB, 220-315us). With (512,2) the allocator
// gets 128 VGPRs (kernel needs ~92, zero spill) and occupancy is limited by
// LDS at the intended 2 blocks/CU (64 KB x 2 = 128 KB <= 160 KB).
// ---------------------------------------------------------------------------
__global__ __launch_bounds__(512, 2) void gemm256_qkv_kernel(
    const unsigned short* __restrict__ A, const unsigned short* __restrict__ Bt,
    const float* __restrict__ b0, const float* __restrict__ b1,
    const float* __restrict__ b2,
    unsigned short* __restrict__ outq, unsigned short* __restrict__ outk,
    unsigned short* __restrict__ outv)
{
    __shared__ __align__(16) unsigned short lds[2 * 16384];   // 64 KB ring

    const int tid  = threadIdx.x;
    const int lane = tid & 63;
    const int wave = tid >> 6;
    const int l15  = lane & 15, quad = lane >> 4;
    const int wm   = wave >> 2, wn = wave & 3;
    // T1: XCD-aware bijective block swizzle (grid (12,16) = 192 = 8*24)
    const int bid  = blockIdx.y * 12 + blockIdx.x;
    const int swz  = (bid & 7) * 24 + (bid >> 3);
    const int m0   = (swz / 12) * 256, n0 = (swz % 12) * 256;

    const int lrow = lane >> 2;
    const int csw  = ((lane & 3) ^ ((lane >> 3) & 3)) * 8;   // swizzled src col (ushorts)
    const int sw8  = (quad ^ ((l15 >> 1) & 3)) * 8;          // swizzled read slot (ushorts)

    // half h of a tile's staging: h=0 -> rows +0..15; h=1 -> rows +16..31.
#define STAGE_H(tt, h) do {                                                    \
        const int bi_ = ((tt) & 1) << 14;                                      \
        const int k0_ = (tt) << 5;                                             \
        const int ra_ = m0 + wave*32 + (h)*16 + lrow;                          \
        const int rb_ = n0 + wave*32 + (h)*16 + lrow;                          \
        gload16(&A [(size_t)ra_*C_ + k0_ + csw],                               \
                &lds[bi_ + wave*1024 + (h)*512]);                              \
        gload16(&Bt[(size_t)rb_*C_ + k0_ + csw],                               \
                &lds[bi_ + 8192 + wave*1024 + (h)*512]);                       \
    } while (0)

    const f32x4 zero4 = {0.f, 0.f, 0.f, 0.f};
    f32x4 acc[8][4];
    #pragma unroll
    for (int i = 0; i < 8; ++i)
        #pragma unroll
        for (int j = 0; j < 4; ++j) acc[i][j] = zero4;

    STAGE_H(0,0); STAGE_H(0,1);       // tile 0 in flight (4 loads)

    for (int t = 0; t < 32; ++t) {
        const int bi = (t & 1) << 14;
        __builtin_amdgcn_s_barrier();            // everyone done reading slot t^1
        __builtin_amdgcn_sched_barrier(0);
        // only tile t's own 4 loads are outstanding here (issued 1 phase ago)
        asm volatile("s_waitcnt vmcnt(0)" ::: "memory");
        __builtin_amdgcn_s_barrier();            // tile t resident for ALL waves
        __builtin_amdgcn_sched_barrier(0);

        const unsigned short* Ab = &lds[bi];
        const unsigned short* Bb = &lds[bi + 8192];

        // ---- phase 1: rows [0,64); stage half 0 of tile t+1 under MFMA ----
        bf16x8 bfr[4], af[4];
        #pragma unroll
        for (int j = 0; j < 4; ++j)
            bfr[j] = *(const bf16x8*)&Bb[(wn*64 + j*16 + l15)*32 + sw8];
        #pragma unroll
        for (int i = 0; i < 4; ++i)
            af[i] = *(const bf16x8*)&Ab[(wm*128 + i*16 + l15)*32 + sw8];

        if (t < 31) STAGE_H(t + 1, 0);

        __builtin_amdgcn_s_setprio(1);
        #pragma unroll
        for (int i = 0; i < 4; ++i)
            #pragma unroll
            for (int j = 0; j < 4; ++j)
                acc[i][j] = __builtin_amdgcn_mfma_f32_16x16x32_bf16(
                    af[i], bfr[j], acc[i][j], 0, 0, 0);
        __builtin_amdgcn_s_setprio(0);

        // ---- phase split: issue-order diversity across waves ----
        __builtin_amdgcn_s_barrier();
        __builtin_amdgcn_sched_barrier(0);

        // ---- phase 2: rows [64,128); stage half 1 of tile t+1 ----
        #pragma unroll
        for (int i = 0; i < 4; ++i)
            af[i] = *(const bf16x8*)&Ab[(wm*128 + 64 + i*16 + l15)*32 + sw8];

        if (t < 31) STAGE_H(t + 1, 1);

        __builtin_amdgcn_s_setprio(1);
        #pragma unroll
        for (int i = 0; i < 4; ++i)
            #pragma unroll
            for (int j = 0; j < 4; ++j)
                acc[4+i][j] = __builtin_amdgcn_mfma_f32_16x16x32_bf16(
                    af[i], bfr[j], acc[4+i][j], 0, 0, 0);
        __builtin_amdgcn_s_setprio(0);
    }
#undef STAGE_H

    // ---- epilogue: ring reused as 8 x 8 KB wave-private staging (2 passes,
    //      purely within-wave: write own region, read own region) ----
    __syncthreads();   // full drain + barrier (one-time)

    unsigned short* Ep = &lds[wave * 4096];      // 8 KB per wave
    const int which = n0 >> 10;                  // 0=q 1=k 2=v
    const int c0 = (n0 & 1023) + wn * 64;        // col within matrix (head base)
    const int h  = c0 >> 6;
    const int bb = m0 >> 11;
    const int t0 = (m0 & (T_ - 1)) + wm * 128;
    const int bh = bb * H_ + h;
    const float* bp = (which == 0) ? b0 : (which == 1 ? b1 : b2);
    // q pre-scale folds softmax 1/sqrt(d) AND 1/ln2 (exp2-direct in flash):
    const float qscale = (which == 0) ? 0.18033688f : 1.0f;   // 0.125/ln(2)

    if (which < 2) {
        // two 64-row halves: [local t=64][d=64] row-major, then coalesced store
        unsigned short* op = (which == 0) ? outq : outk;
        __bf16* Eb = (__bf16*)Ep;
        const int row8 = lane >> 3, chunk = lane & 7;
        #pragma unroll
        for (int hb = 0; hb < 2; ++hb) {
            #pragma unroll
            for (int j = 0; j < 4; ++j) {
                const int cl = j*16 + l15;
                const float bias = bp[c0 + cl];
                #pragma unroll
                for (int i = 0; i < 4; ++i)
                    #pragma unroll
                    for (int r = 0; r < 4; ++r)
                        Eb[(i*16 + quad*4 + r)*64 + cl] =
                            (__bf16)((acc[hb*4 + i][j][r] + bias) * qscale);
            }
            #pragma unroll
            for (int u = 0; u < 8; ++u) {
                const int row = u*8 + row8;      // local row 0..63
                const uint4 v = *(const uint4*)&Ep[row*64 + chunk*8];
                *(uint4*)&op[((size_t)bh*T_ + t0 + hb*64 + row)*D_ + chunk*8] = v;
            }
        }
    } else {
        // two 32-d halves: [local d=32][t=128] with XOR slot swizzle
        const int d4 = lane >> 4, chunk = lane & 15;
        #pragma unroll
        for (int hb = 0; hb < 2; ++hb) {
            #pragma unroll
            for (int j = 0; j < 2; ++j) {
                const int cl = (hb*2 + j)*16 + l15;   // d within head, 0..63
                const float bias = bp[c0 + cl];
                const int lcl = cl - hb*32;           // local d 0..31
                const int xo = (cl & 7) * 8;
                #pragma unroll
                for (int i = 0; i < 8; ++i) {
                    bf16x4 pk = {(__bf16)(acc[i][hb*2 + j][0] + bias),
                                 (__bf16)(acc[i][hb*2 + j][1] + bias),
                                 (__bf16)(acc[i][hb*2 + j][2] + bias),
                                 (__bf16)(acc[i][hb*2 + j][3] + bias)};
                    *(bf16x4*)&Ep[lcl*128 + ((i*16 + quad*4) ^ xo)] = pk;
                }
            }
            #pragma unroll
            for (int u = 0; u < 8; ++u) {
                const int d = hb*32 + u*4 + d4;
                const uint4 v = *(const uint4*)
                    &Ep[(d - hb*32)*128 + ((chunk*8) ^ ((d & 7)*8))];
                *(uint4*)&outv[((size_t)bh*D_ + d)*T_ + t0 + chunk*8] = v;
            }
        }
    }
}

// ---------------------------------------------------------------------------
// MFMA flash attention v8: 32x32x16 MFMA + in-register softmax (T12).
// Verified rounds 7-12 (~42 us).
// ---------------------------------------------------------------------------
__global__ __launch_bounds__(256) void flash_mfma_kernel(
    const unsigned short* __restrict__ Qs, const unsigned short* __restrict__ Ks,
    const unsigned short* __restrict__ Vts, unsigned short* __restrict__ Y,
    float* __restrict__ parts, float* __restrict__ lbase)
{
    __shared__ __align__(16) unsigned short Kls[64 * 64];   // 8 KB, swizzled
    __shared__ __align__(16) unsigned short Vls[64 * 64];   // 8 KB, swizzled
    __shared__ float lsums[4][32];

    const int tid  = threadIdx.x;
    const int lane = tid & 63, wave = tid >> 6;
    const int krl  = lane & 31, hi = lane >> 5;
    const int srow8 = lane >> 3;                  // 0..7 (staging row-in-cu)
    const int schk8 = ((lane & 7) ^ srow8) * 8;   // pre-swizzled src chunk (ushorts)
    const int job  = blockIdx.x >> 5;    // 0..15
    const int bh   = blockIdx.x & 31;
    const bool isA = (job < 8);
    const int a    = isA ? job : job - 8;

    int qts[2], slos[2], shis[2], slots[2], nseg;
    if (isA) {
        qts[0] = a;      slos[0] = 0;        shis[0] = 2*a + 2;  slots[0] = -1;
        qts[1] = 15 - a; slos[1] = 0;        shis[1] = 15 - 2*a; slots[1] = 0;
        nseg = 2;
    } else {
        qts[0] = 15 - a; slos[0] = 15 - 2*a; shis[0] = 32 - 2*a; slots[0] = 1;
        nseg = 1;
    }

    const int b_ = bh >> 4, h_ = bh & (H_ - 1);

#define FSTAGE(itv) do {                                                       \
        const int s0_ = (itv) * 64;                                            \
        const int cu0_ = 2*wave, cu1_ = 2*wave + 1;                            \
        const int r0_ = cu0_*8 + srow8, r1_ = cu1_*8 + srow8;                  \
        gload16(&Ks [((size_t)bh*T_ + s0_ + r0_)*D_ + schk8],                  \
                (char*)Kls + cu0_*1024);                                       \
        gload16(&Vts[((size_t)bh*D_ + r0_)*T_ + s0_ + schk8],                  \
                (char*)Vls + cu0_*1024);                                       \
        gload16(&Ks [((size_t)bh*T_ + s0_ + r1_)*D_ + schk8],                  \
                (char*)Kls + cu1_*1024);                                       \
        gload16(&Vts[((size_t)bh*D_ + r1_)*T_ + s0_ + schk8],                  \
                (char*)Vls + cu1_*1024);                                       \
    } while (0)

    for (int sg = 0; sg < nseg; ++sg) {
        const int qt  = qts[sg];
        const int qw0 = qt * 128 + wave * 32;
        const int qrow = qw0 + krl;              // this lane's q-column

        // Q fragments (B-operand, d-slices of 16): contiguous 16B from global
        bf16x8 qf[4];
        #pragma unroll
        for (int ds = 0; ds < 4; ++ds)
            qf[ds] = *(const bf16x8*)&Qs[((size_t)bh*T_ + qrow)*D_ + ds*16 + hi*8];

        f32x16 o[2];
        #pragma unroll
        for (int dt = 0; dt < 2; ++dt)
            #pragma unroll
            for (int r = 0; r < 16; ++r) o[dt][r] = 0.f;
        float lsum = 0.f;

        for (int it = slos[sg]; it < shis[sg]; ++it) {
            const int s0 = it * 64;
            __syncthreads();
            FSTAGE(it);
            __syncthreads();

            if (s0 > qw0 + 31) continue;   // wave fully masked (uniform barriers)

            // ---- S^T = K·Q^T (2 k-tiles x 4 d-slices, 32x32x16) ----
            f32x16 st[2];
            #pragma unroll
            for (int kt = 0; kt < 2; ++kt)
                #pragma unroll
                for (int r = 0; r < 16; ++r) st[kt][r] = 0.f;
            #pragma unroll
            for (int kt = 0; kt < 2; ++kt) {
                #pragma unroll
                for (int ds = 0; ds < 4; ++ds) {
                    const int row = kt*32 + krl;
                    bf16x8 kf = *(const bf16x8*)
                        &Kls[row*64 + (((ds*2 + hi) ^ (krl & 7)) << 3)];
                    st[kt] = __builtin_amdgcn_mfma_f32_32x32x16_bf16(
                        kf, qf[ds], st[kt], 0, 0, 0);
                }
            }

            // ---- p = 2^s (+ causal mask), in-register; accumulate lsum ----
            const bool diag = (s0 + 63 > qw0);
            #pragma unroll
            for (int kt = 0; kt < 2; ++kt) {
                const int kb = s0 + kt*32 + 4*hi;
                #pragma unroll
                for (int reg = 0; reg < 16; ++reg) {
                    const int crow = (reg & 3) + 8*(reg >> 2);
                    float e = __builtin_amdgcn_exp2f(st[kt][reg]);
                    if (diag && (kb + crow > qrow)) e = 0.f;
                    st[kt][reg] = e;
                    lsum += e;
                }
            }

            // ---- pack P -> PV A-fragments (cvt_pk + permlane32_swap) ----
            bf16x8 pa[4];
            #pragma unroll
            for (int kt = 0; kt < 2; ++kt) {
                #pragma unroll
                for (int hh = 0; hh < 2; ++hh) {
                    const int rb = hh * 8;
                    unsigned c0, c1, c2, c3;
                    asm("v_cvt_pk_bf16_f32 %0, %1, %2"
                        : "=v"(c0) : "v"(st[kt][rb+0]), "v"(st[kt][rb+1]));
                    asm("v_cvt_pk_bf16_f32 %0, %1, %2"
                        : "=v"(c1) : "v"(st[kt][rb+2]), "v"(st[kt][rb+3]));
                    asm("v_cvt_pk_bf16_f32 %0, %1, %2"
                        : "=v"(c2) : "v"(st[kt][rb+4]), "v"(st[kt][rb+5]));
                    asm("v_cvt_pk_bf16_f32 %0, %1, %2"
                        : "=v"(c3) : "v"(st[kt][rb+6]), "v"(st[kt][rb+7]));
                    asm("v_permlane32_swap_b32 %0, %1" : "+v"(c0), "+v"(c2));
                    asm("v_permlane32_swap_b32 %0, %1" : "+v"(c1), "+v"(c3));
                    pa[kt*2 + hh] = pack4(c0, c1, c2, c3);
                }
            }

            // ---- O += P·V (2 d-tiles x 4 k-slices, 32x32x16) ----
            #pragma unroll
            for (int dt = 0; dt < 2; ++dt) {
                #pragma unroll
                for (int ks = 0; ks < 4; ++ks) {
                    const int rowd = dt*32 + krl;
                    bf16x8 vb = *(const bf16x8*)
                        &Vls[rowd*64 + (((ks*2 + hi) ^ (krl & 7)) << 3)];
                    o[dt] = __builtin_amdgcn_mfma_f32_32x32x16_bf16(
                        pa[ks], vb, o[dt], 0, 0, 0);
                }
            }
        }

        // ---- combine lane-halves of lsum; publish per-q sums ----
        lsum += __shfl_xor(lsum, 32, 64);
        if (lane < 32) lsums[wave][krl] = lsum;

        if (slots[sg] < 0) {
            // direct write Y bf16 (O layout: col d = krl, row q = crow+4*hi)
            #pragma unroll
            for (int reg = 0; reg < 16; ++reg) {
                const int q = (reg & 3) + 8*(reg >> 2) + 4*hi;
                const float inv = 1.0f / lsums[wave][q];
                const size_t yb = ((size_t)(b_*T_ + qw0 + q))*C_ + h_*D_;
                *(__bf16*)&Y[yb + krl]      = (__bf16)(o[0][reg] * inv);
                *(__bf16*)&Y[yb + 32 + krl] = (__bf16)(o[1][reg] * inv);
            }
        } else {
            // partial: fp32 O [128][64] + l [128] into slot
            const int gpi = bh*16 + a*2 + slots[sg];
            float* Op = parts + (size_t)gpi*8192;
            float* Lp = lbase + gpi*128;
            if (lane < 32) Lp[wave*32 + lane] = lsum;
            #pragma unroll
            for (int reg = 0; reg < 16; ++reg) {
                const int tl = wave*32 + (reg & 3) + 8*(reg >> 2) + 4*hi;
                Op[(size_t)tl*64 + krl]      = o[0][reg];
                Op[(size_t)tl*64 + 32 + krl] = o[1][reg];
            }
        }
    }
#undef FSTAGE
}

// ---------------------------------------------------------------------------
// Merge split partials: Y = (O0+O1)/(l0+l1), bf16. Grid 256 (32 bh x 8 pairs).
// Pair p merges qt = 15-p from slots (bh*16+p*2, +1); O is [128][64].
// ---------------------------------------------------------------------------
__global__ __launch_bounds__(256) void merge_kernel(
    const float* __restrict__ parts, const float* __restrict__ lbase,
    unsigned short* __restrict__ Y)
{
    const int pair = blockIdx.x;          // 0..255
    const int bh = pair >> 3, p = pair & 7;
    const int qt = 15 - p;
    const int g0 = bh*16 + p*2;
    const float* O0 = parts + (size_t)g0*8192;
    const float* O1 = O0 + 8192;
    const float* L0 = lbase + g0*128;
    const float* L1 = L0 + 128;

    const int tid = threadIdx.x;
    const int r = tid >> 1, c0 = (tid & 1) * 32;
    const float inv = 1.0f / (L0[r] + L1[r]);
    const int b = bh >> 4, h = bh & (H_ - 1);
    const int t = qt*128 + r;
    #pragma unroll
    for (int k = 0; k < 8; ++k) {
        const f32x4 a  = *(const f32x4*)&O0[(size_t)r*64 + c0 + k*4];
        const f32x4 bb = *(const f32x4*)&O1[(size_t)r*64 + c0 + k*4];
        bf16x4 pk = {(__bf16)((a[0]+bb[0])*inv), (__bf16)((a[1]+bb[1])*inv),
                     (__bf16)((a[2]+bb[2])*inv), (__bf16)((a[3]+bb[3])*inv)};
        *(bf16x4*)&Y[((size_t)(b*T_ + t))*C_ + h*D_ + c0 + k*4] = pk;
    }
}

// ---------------------------------------------------------------------------
extern "C" void kernel_launch(void* const* d_in, const int* in_sizes, int n_in,
                              void* d_out, int out_size, void* d_ws, size_t ws_size,
                              hipStream_t stream) {
    const float* query = (const float*)d_in[0];
    const float* Wq = (const float*)d_in[1];
    const float* bq = (const float*)d_in[2];
    const float* Wk = (const float*)d_in[3];
    const float* bk = (const float*)d_in[4];
    const float* Wv = (const float*)d_in[5];
    const float* bv = (const float*)d_in[6];
    const float* Wp = (const float*)d_in[7];
    const float* bp = (const float*)d_in[8];
    float* out = (float*)d_out;

    // Workspace layout (bytes), total 50.33 MB:
    //   [0,       8.39M)  q bf16 [bh][t][d], pre-scaled by 0.125/ln2
    //   [8.39M,  16.78M)  k bf16 [bh][t][d]
    //   [16.78M, 25.17M)  v bf16 [bh][d][t] (transposed)
    //   [25.17M, 27.26M)  WtP   bf16 (Wp^T)
    //   [27.26M, 33.55M)  WtQKV bf16; dead after QKV GEMM -> lbase (512x128 f32)
    //   [33.55M, 41.94M)  yb    bf16 [B*T][C] (attention output)
    //   [41.94M, 50.33M)  qx    bf16 query (dead after QKV GEMM)
    // Flash O-partials (512 x 32KB fp32 = 16.78MB) live in d_out, which is
    // dead until the proj GEMM overwrites it at the end.
    char* ws = (char*)d_ws;
    unsigned short* qbf   = (unsigned short*)(ws);
    unsigned short* kbf   = (unsigned short*)(ws + 8388608);
    unsigned short* vtbf  = (unsigned short*)(ws + 16777216);
    unsigned short* WtP   = (unsigned short*)(ws + 25165824);
    unsigned short* WtQKV = (unsigned short*)(ws + 27262976);
    unsigned short* yb    = (unsigned short*)(ws + 33554432);
    unsigned short* qx    = (unsigned short*)(ws + 41943040);
    float* lbase = (float*)(ws + 27262976);             // 512 x 128 floats
    float* parts = out;                                 // 512 x 8192 floats

    prep_kernel<<<6144, 256, 0, stream>>>(
        query, qx, Wq, Wk, Wv, Wp,
        WtQKV, WtQKV + (size_t)C_*C_, WtQKV + 2*(size_t)C_*C_, WtP);

    // Fused QKV GEMM v5b: M=4096, N=3072, 2-slot ring, 2 blocks/CU (LDS-limited)
    gemm256_qkv_kernel<<<dim3(12, 16), 512, 0, stream>>>(
        qx, WtQKV, bq, bk, bv, qbf, kbf, vtbf);

    flash_mfma_kernel<<<512, 256, 0, stream>>>(qbf, kbf, vtbf, yb, parts, lbase);
    merge_kernel<<<256, 256, 0, stream>>>(parts, lbase, yb);

    // Output projection v3: M=4096, N=1024, in-phase-staged ring
    gemm_proj_kernel<<<dim3(C_/128, M_/64), 256, 0, stream>>>(
        yb, WtP, bp, out);
}